// Round 2
// baseline (1962.389 us; speedup 1.0000x reference)
//
#include <hip/hip_runtime.h>
#include <math.h>

#define NN 100000
#define EE 640000
#define DD 128
#define NB_SCAN ((NN + 255) / 256)   // 391

static __device__ __forceinline__ float4 ld4(const float* p) {
    return *reinterpret_cast<const float4*>(p);
}
static __device__ __forceinline__ void st4(float* p, float4 v) {
    *reinterpret_cast<float4*>(p) = v;
}

// ---------------------------------------------------------------------------
// Fused GEMM:  out[:, co:co+128] = act( (A(*Amask, reluA?) @ W + bias + addend) * pmask )
// A: [M,K] row-major (lda == K). W: [K,128] row-major. act: 0 none, 1 relu, 2 sigmoid.
// BM=64, BN=128, BK=64. 256 threads: tx = tid&31 -> 4 cols, ty = tid>>5 -> 8 rows.
// ---------------------------------------------------------------------------
template<int K>
__launch_bounds__(256, 3)
__global__ void gemm_k(const float* A,
                       const float* __restrict__ Amask,
                       const int reluA,
                       const float* __restrict__ W,
                       const float* __restrict__ bias,
                       const float* __restrict__ addend,
                       const float* __restrict__ pmask,
                       const int act,
                       float* out, const int ldo, const int co, const int M)
{
    __shared__ __align__(16) float As[64][68];   // pad 4 floats: 272B row, 16B aligned
    __shared__ __align__(16) float Ws[64][128];

    const int t  = threadIdx.x;
    const int tx = t & 31;     // col group: cols tx*4 .. tx*4+3
    const int ty = t >> 5;     // row group: rows ty*8 .. ty*8+7
    const int brow = blockIdx.x * 64;

    float4 acc[8];
#pragma unroll
    for (int i = 0; i < 8; ++i) acc[i] = make_float4(0.f, 0.f, 0.f, 0.f);

    for (int kt = 0; kt < K / 64; ++kt) {
        // ---- stage A tile [64 rows x 64 k] (row-major in LDS) ----
        {
            const int k4 = t & 15, mr = t >> 4;
#pragma unroll
            for (int it = 0; it < 4; ++it) {
                const int m = mr + it * 16;
                int grow = brow + m; if (grow >= M) grow = M - 1;  // clamp stays in-block
                const int gk = kt * 64 + k4 * 4;
                float4 v = ld4(A + (size_t)grow * K + gk);
                if (Amask) {   // only used for K==128 paths (mask stride = DD)
                    const float4 mm = ld4(Amask + (size_t)grow * DD + gk);
                    v.x *= mm.x; v.y *= mm.y; v.z *= mm.z; v.w *= mm.w;
                }
                if (reluA) {
                    v.x = fmaxf(v.x, 0.f); v.y = fmaxf(v.y, 0.f);
                    v.z = fmaxf(v.z, 0.f); v.w = fmaxf(v.w, 0.f);
                }
                st4(&As[m][k4 * 4], v);
            }
            // ---- stage W tile [64 k x 128 cols] ----
            const int c4 = t & 31, kr0 = t >> 5;
#pragma unroll
            for (int it = 0; it < 8; ++it) {
                const int kr = kr0 + it * 8;
                const float4 v = ld4(W + (size_t)(kt * 64 + kr) * DD + c4 * 4);
                st4(&Ws[kr][c4 * 4], v);
            }
        }
        __syncthreads();

#pragma unroll 4
        for (int kk = 0; kk < 16; ++kk) {
            const float4 w0 = ld4(&Ws[kk * 4 + 0][tx * 4]);
            const float4 w1 = ld4(&Ws[kk * 4 + 1][tx * 4]);
            const float4 w2 = ld4(&Ws[kk * 4 + 2][tx * 4]);
            const float4 w3 = ld4(&Ws[kk * 4 + 3][tx * 4]);
#pragma unroll
            for (int i = 0; i < 8; ++i) {
                const float4 a = ld4(&As[ty * 8 + i][kk * 4]);
                acc[i].x += a.x * w0.x + a.y * w1.x + a.z * w2.x + a.w * w3.x;
                acc[i].y += a.x * w0.y + a.y * w1.y + a.z * w2.y + a.w * w3.y;
                acc[i].z += a.x * w0.z + a.y * w1.z + a.z * w2.z + a.w * w3.z;
                acc[i].w += a.x * w0.w + a.y * w1.w + a.z * w2.w + a.w * w3.w;
            }
        }
        __syncthreads();
    }

    // ---- epilogue ----
    float4 b4 = make_float4(0.f, 0.f, 0.f, 0.f);
    if (bias) b4 = ld4(bias + tx * 4);
#pragma unroll
    for (int i = 0; i < 8; ++i) {
        const int row = brow + ty * 8 + i;
        if (row < M) {
            float4 v = acc[i];
            v.x += b4.x; v.y += b4.y; v.z += b4.z; v.w += b4.w;
            if (addend) {
                const float4 ad = ld4(addend + (size_t)row * DD + tx * 4);
                v.x += ad.x; v.y += ad.y; v.z += ad.z; v.w += ad.w;
            }
            if (pmask) {
                const float4 pm = ld4(pmask + (size_t)row * DD + tx * 4);
                v.x *= pm.x; v.y *= pm.y; v.z *= pm.z; v.w *= pm.w;
            }
            if (act == 1) {
                v.x = fmaxf(v.x, 0.f); v.y = fmaxf(v.y, 0.f);
                v.z = fmaxf(v.z, 0.f); v.w = fmaxf(v.w, 0.f);
            } else if (act == 2) {
                v.x = 1.f / (1.f + __expf(-v.x));
                v.y = 1.f / (1.f + __expf(-v.y));
                v.z = 1.f / (1.f + __expf(-v.z));
                v.w = 1.f / (1.f + __expf(-v.w));
            }
            st4(out + (size_t)row * ldo + co + tx * 4, v);
        }
    }
}

// ---------------------------------------------------------------------------
// SPMM (CSR by dst): out[n,:] = sum_j val[j] * H[col[j], :].  One wave per node.
// ---------------------------------------------------------------------------
__launch_bounds__(256)
__global__ void spmm_k(const float* __restrict__ H,
                       const int* __restrict__ rp,
                       const int* __restrict__ ccol,
                       const float* __restrict__ cval,
                       float* __restrict__ out, const int ldo)
{
    const int w = (blockIdx.x * 256 + threadIdx.x) >> 6;
    if (w >= NN) return;
    const int lane = threadIdx.x & 63;
    const int s = rp[w], e = rp[w + 1];
    float ax = 0.f, ay = 0.f;
    int j = s;
    while (j < e) {
        int cnt = e - j; if (cnt > 8) cnt = 8;
        int cols[8]; float vals[8];
#pragma unroll
        for (int q = 0; q < 8; ++q) {
            if (q < cnt) { cols[q] = ccol[j + q]; vals[q] = cval[j + q]; }
        }
#pragma unroll
        for (int q = 0; q < 8; ++q) {
            if (q < cnt) {
                const float2 hv = *reinterpret_cast<const float2*>(
                    H + (size_t)cols[q] * DD + lane * 2);
                ax = fmaf(vals[q], hv.x, ax);
                ay = fmaf(vals[q], hv.y, ay);
            }
        }
        j += cnt;
    }
    float2 o; o.x = ax; o.y = ay;
    *reinterpret_cast<float2*>(out + (size_t)w * ldo + lane * 2) = o;
}

// ---------------------------------------------------------------------------
// CSR build kernels
// ---------------------------------------------------------------------------
__global__ void hist_k(const int* __restrict__ dstI, int* __restrict__ counts) {
    const int e = blockIdx.x * 256 + threadIdx.x;
    if (e < EE) atomicAdd(&counts[dstI[e]], 1);
}

__global__ void block_sums_k(const int* __restrict__ counts, int* __restrict__ bsum) {
    __shared__ int s[256];
    const int t = threadIdx.x;
    const int i = blockIdx.x * 256 + t;
    s[t] = (i < NN) ? counts[i] : 0;
    __syncthreads();
    for (int off = 128; off > 0; off >>= 1) {
        if (t < off) s[t] += s[t + off];
        __syncthreads();
    }
    if (t == 0) bsum[blockIdx.x] = s[0];
}

__global__ void scan_bsums_k(const int* __restrict__ bsum, int* __restrict__ bpre, const int nb) {
    __shared__ int s[512];
    const int t = threadIdx.x;
    s[t] = (t < nb) ? bsum[t] : 0;
    __syncthreads();
    for (int off = 1; off < 512; off <<= 1) {
        const int tmp = (t >= off) ? s[t - off] : 0;
        __syncthreads();
        s[t] += tmp;
        __syncthreads();
    }
    if (t < nb) bpre[t] = (t == 0) ? 0 : s[t - 1];
}

__global__ void scan_final_k(const int* __restrict__ counts, const int* __restrict__ bpre,
                             int* __restrict__ rowptr, int* __restrict__ nextc) {
    __shared__ int s[256];
    const int t = threadIdx.x;
    const int i = blockIdx.x * 256 + t;
    const int v = (i < NN) ? counts[i] : 0;
    s[t] = v;
    __syncthreads();
    for (int off = 1; off < 256; off <<= 1) {
        const int tmp = (t >= off) ? s[t - off] : 0;
        __syncthreads();
        s[t] += tmp;
        __syncthreads();
    }
    const int excl = s[t] - v + bpre[blockIdx.x];
    if (i < NN) { rowptr[i] = excl; nextc[i] = excl; }
    if (i == NN - 1) rowptr[NN] = EE;
}

__global__ void scatter_k(const int* __restrict__ srcI, const int* __restrict__ dstI,
                          const float* __restrict__ ea, int* __restrict__ nextc,
                          int* __restrict__ ccol, float* __restrict__ cval) {
    const int e = blockIdx.x * 256 + threadIdx.x;
    if (e >= EE) return;
    const int d = dstI[e];
    const int p = atomicAdd(&nextc[d], 1);
    ccol[p] = srcI[e];
    cval[p] = ea[e];
}

// ---------------------------------------------------------------------------
extern "C" void kernel_launch(void* const* d_in, const int* in_sizes, int n_in,
                              void* d_out, int out_size, void* d_ws, size_t ws_size,
                              hipStream_t stream)
{
    const float* x_in0      = (const float*)d_in[0];
    const float* edge_attr  = (const float*)d_in[1];
    const int*   edge_index = (const int*)d_in[2];
    const float* conv_w     = (const float*)d_in[3];
    const float* conv_lin_w = (const float*)d_in[4];
    const float* l1_w       = (const float*)d_in[5];
    const float* l1_b       = (const float*)d_in[6];
    const float* l2_w       = (const float*)d_in[7];
    const float* l2_b       = (const float*)d_in[8];
    const float* mlp1_w     = (const float*)d_in[9];
    const float* mlp1_b     = (const float*)d_in[10];
    const float* mlp2_w     = (const float*)d_in[11];
    const float* mlp2_b     = (const float*)d_in[12];
    const float* post1_w    = (const float*)d_in[13];
    const float* post1_b    = (const float*)d_in[14];
    const float* post2_w    = (const float*)d_in[15];
    const float* post2_b    = (const float*)d_in[16];

    const int* srcI = edge_index;        // edge_index[0, :]
    const int* dstI = edge_index + EE;   // edge_index[1, :]

    // d_out doubles as the x ping buffer (written before ever read; in-place
    // update is safe: each GEMM block reads only its own rows and writes them
    // only after its last k-tile + barrier).
    float* x_ws = (float*)d_out;

    // workspace layout (~211 MB)
    float* maskbuf = (float*)d_ws;                     // [NN, DD]
    float* h       = maskbuf + (size_t)NN * DD;        // [NN, DD]
    float* cat     = h + (size_t)NN * DD;              // [NN, 2*DD]
    int*   rowptr  = (int*)(cat + (size_t)NN * 2 * DD);// [NN+1]
    int*   nextc   = rowptr + (NN + 1);                // [NN]
    int*   counts  = nextc + NN;                       // [NN]
    int*   bsum    = counts + NN;                      // [512]
    int*   bpre    = bsum + 512;                       // [512]
    int*   ccol    = bpre + 512;                       // [EE]
    float* cval    = (float*)(ccol + EE);              // [EE]

    // ---- build CSR (dst-sorted) once per call ----
    hipMemsetAsync(counts, 0, NN * sizeof(int), stream);
    hist_k      <<<(EE + 255) / 256, 256, 0, stream>>>(dstI, counts);
    block_sums_k<<<NB_SCAN, 256, 0, stream>>>(counts, bsum);
    scan_bsums_k<<<1, 512, 0, stream>>>(bsum, bpre, NB_SCAN);
    scan_final_k<<<NB_SCAN, 256, 0, stream>>>(counts, bpre, rowptr, nextc);
    scatter_k   <<<(EE + 255) / 256, 256, 0, stream>>>(srcI, dstI, edge_attr, nextc, ccol, cval);

    const int GB = (NN + 63) / 64;       // 1563 blocks
    const int SPMM_GRID = NN * 64 / 256; // 25000 blocks

    for (int i = 0; i < 3; ++i) {
        const float* xc = (i == 0) ? x_in0 : x_ws;
        const float* pm = (i == 0) ? nullptr : maskbuf;  // previous-layer mask
        // h = xm @ l1_w + l1_b
        gemm_k<128><<<GB, 256, 0, stream>>>(xc, pm, 0, l1_w + (size_t)i * DD * DD,
                                            l1_b + i * DD, nullptr, nullptr, 0, h, DD, 0, NN);
        // cat[:, 0:128] = agg(h)
        spmm_k<<<SPMM_GRID, 256, 0, stream>>>(h, rowptr, ccol, cval, cat, 2 * DD);
        // cat[:, 128:256] = xm @ l2_w + l2_b
        gemm_k<128><<<GB, 256, 0, stream>>>(xc, pm, 0, l2_w + (size_t)i * DD * DD,
                                            l2_b + i * DD, nullptr, nullptr, 0, cat, 2 * DD, DD, NN);
        // w = relu(relu(cat) @ mlp1_w + mlp1_b)   (stored in h)
        gemm_k<256><<<GB, 256, 0, stream>>>(cat, nullptr, 1, mlp1_w + (size_t)i * 2 * DD * DD,
                                            mlp1_b + i * DD, nullptr, nullptr, 1, h, DD, 0, NN);
        // mask = sigmoid(w @ mlp2_w + mlp2_b)
        gemm_k<128><<<GB, 256, 0, stream>>>(h, nullptr, 0, mlp2_w + (size_t)i * DD * DD,
                                            mlp2_b + i * DD, nullptr, nullptr, 2, maskbuf, DD, 0, NN);
        // h2 = (x * mask) @ conv_w   (stored in cat, stride 128)
        gemm_k<128><<<GB, 256, 0, stream>>>(xc, maskbuf, 0, conv_w + (size_t)i * DD * DD,
                                            nullptr, nullptr, nullptr, 0, cat, DD, 0, NN);
        // agg2 = agg(h2)   (stored in h)
        spmm_k<<<SPMM_GRID, 256, 0, stream>>>(cat, rowptr, ccol, cval, h, DD);
        // x = relu((agg2 + x @ conv_lin_w) * mask)
        gemm_k<128><<<GB, 256, 0, stream>>>(xc, nullptr, 0, conv_lin_w + (size_t)i * DD * DD,
                                            nullptr, h, maskbuf, 1, x_ws, DD, 0, NN);
    }
    // y1 = relu(x @ post1_w + post1_b)
    gemm_k<128><<<GB, 256, 0, stream>>>(x_ws, nullptr, 0, post1_w, post1_b,
                                        nullptr, nullptr, 1, h, DD, 0, NN);
    // out = y1 @ post2_w + post2_b
    gemm_k<128><<<GB, 256, 0, stream>>>(h, nullptr, 0, post2_w, post2_b,
                                        nullptr, nullptr, 0, (float*)d_out, DD, 0, NN);
    (void)in_sizes; (void)n_in; (void)out_size; (void)ws_size;
}

// Round 3
// 1669.251 us; speedup vs baseline: 1.1756x; 1.1756x over previous
//
#include <hip/hip_runtime.h>
#include <math.h>

#define NN 100000
#define EE 640000
#define DD 128
#define NB_SCAN ((NN + 255) / 256)   // 391

typedef __attribute__((ext_vector_type(8))) short bf16x8;
typedef __attribute__((ext_vector_type(4))) float f32x4;

static __device__ __forceinline__ float4 ld4(const float* p) {
    return *reinterpret_cast<const float4*>(p);
}

// split fp32 a into hi+lo bf16 (both RNE): a ~= hi + lo, |lo| <= 2^-9 |a|
static __device__ __forceinline__ void splitbf(float a, unsigned short& hi, unsigned short& lo) {
    unsigned u = __float_as_uint(a);
    unsigned hr = (u + 0x7FFFu + ((u >> 16) & 1u)) >> 16;
    float hf = __uint_as_float(hr << 16);
    float l = a - hf;
    unsigned ul = __float_as_uint(l);
    unsigned lr = (ul + 0x7FFFu + ((ul >> 16) & 1u)) >> 16;
    hi = (unsigned short)hr; lo = (unsigned short)lr;
}

// ---------------------------------------------------------------------------
// W-fragment pre-pack: for each weight matrix, store bf16 hi/lo fragments in
// the exact B-operand order of mfma_f32_16x16x32_bf16:
//   frag[((ks*8+ct)*64+lane)*8 + r] = W[ks*32 + (lane>>4)*8 + r][ct*16 + (lane&15)]
// Segments (in 32-row k-slices): l1 12@0, l2 12@49152, mlp1 24@98304 (K=256),
// mlp2 12@196608, conv 12@245760, convlin 12@294912, post1 4@344064, post2 4@360448.
// ---------------------------------------------------------------------------
__global__ void wfrag_k(const float* __restrict__ l1w, const float* __restrict__ l2w,
                        const float* __restrict__ mlp1w, const float* __restrict__ mlp2w,
                        const float* __restrict__ convw, const float* __restrict__ convlinw,
                        const float* __restrict__ post1w, const float* __restrict__ post2w,
                        unsigned short* __restrict__ Wh, unsigned short* __restrict__ Wl)
{
    const int b = blockIdx.x;
    const float* W; int slice; size_t fbase; int K;
    if (b < 12)      { W = l1w;      slice = b;      fbase = 0;      K = 128; }
    else if (b < 24) { W = l2w;      slice = b - 12; fbase = 49152;  K = 128; }
    else if (b < 48) { W = mlp1w;    slice = b - 24; fbase = 98304;  K = 256; }
    else if (b < 60) { W = mlp2w;    slice = b - 48; fbase = 196608; K = 128; }
    else if (b < 72) { W = convw;    slice = b - 60; fbase = 245760; K = 128; }
    else if (b < 84) { W = convlinw; slice = b - 72; fbase = 294912; K = 128; }
    else if (b < 88) { W = post1w;   slice = b - 84; fbase = 344064; K = 128; }
    else             { W = post2w;   slice = b - 88; fbase = 360448; K = 128; }
    const int kslices = K / 32;
    const int mat = slice / kslices;
    const int ks  = slice % kslices;
    const float* Wm = W + (size_t)mat * K * DD;
    const size_t outb = fbase + (size_t)mat * K * DD + (size_t)ks * 4096;
    const int t = threadIdx.x;
#pragma unroll
    for (int e = 0; e < 16; ++e) {
        const int f = t * 16 + e;
        const int r = f & 7, lane = (f >> 3) & 63, ct = f >> 9;
        const int krow = ks * 32 + (lane >> 4) * 8 + r;
        const int col  = ct * 16 + (lane & 15);
        unsigned short hh, ll;
        splitbf(Wm[(size_t)krow * DD + col], hh, ll);
        Wh[outb + f] = hh; Wl[outb + f] = ll;
    }
}

// ---------------------------------------------------------------------------
// MFMA GEMM (split-bf16, 3 mfma per fp32 product). Wave = 16 rows x 128 cols.
// No LDS, no barriers. KT = K/32.
// mode: 0 single out, 1 dual (out1 shares processed A), 2 dual (out1 uses raw A)
// ---------------------------------------------------------------------------
template<int KT>
__launch_bounds__(256)
__global__ void gemm_mfma(const float* __restrict__ A,
                          const float* __restrict__ Amask, const int reluA,
                          const unsigned short* __restrict__ Wh0, const unsigned short* __restrict__ Wl0,
                          const float* __restrict__ bias0,
                          const float* __restrict__ addend0, const float* __restrict__ pmask0,
                          const int act0, float* __restrict__ out0, const int ldo0, const int co0,
                          const int mode,
                          const unsigned short* __restrict__ Wh1, const unsigned short* __restrict__ Wl1,
                          const float* __restrict__ bias1,
                          float* __restrict__ out1, const int ldo1, const int co1)
{
    const int lane = threadIdx.x & 63;
    const int gw = blockIdx.x * 4 + (threadIdx.x >> 6);
    const int rowbase = gw * 16;
    if (rowbase >= NN) return;
    const int ra = rowbase + (lane & 15);   // A row this lane reads
    const int kg = lane >> 4;               // k-group 0..3

    // ---- load raw A (kept live for mode 2) ----
    float araw[KT][8];
    const float* Ap = A + (size_t)ra * (KT * 32) + kg * 8;
#pragma unroll
    for (int ks = 0; ks < KT; ++ks) {
        const float4 v0 = ld4(Ap + ks * 32);
        const float4 v1 = ld4(Ap + ks * 32 + 4);
        araw[ks][0] = v0.x; araw[ks][1] = v0.y; araw[ks][2] = v0.z; araw[ks][3] = v0.w;
        araw[ks][4] = v1.x; araw[ks][5] = v1.y; araw[ks][6] = v1.z; araw[ks][7] = v1.w;
    }

    // ---- processed (mask/relu) split A ----
    bf16x8 ah[KT], al[KT];
#pragma unroll
    for (int ks = 0; ks < KT; ++ks) {
        float tmp[8];
#pragma unroll
        for (int j = 0; j < 8; ++j) tmp[j] = araw[ks][j];
        if (Amask) {   // only used when K == DD
            const float* mp = Amask + (size_t)ra * DD + ks * 32 + kg * 8;
            const float4 m0 = ld4(mp), m1 = ld4(mp + 4);
            tmp[0] *= m0.x; tmp[1] *= m0.y; tmp[2] *= m0.z; tmp[3] *= m0.w;
            tmp[4] *= m1.x; tmp[5] *= m1.y; tmp[6] *= m1.z; tmp[7] *= m1.w;
        }
        if (reluA) {
#pragma unroll
            for (int j = 0; j < 8; ++j) tmp[j] = fmaxf(tmp[j], 0.f);
        }
#pragma unroll
        for (int j = 0; j < 8; ++j) {
            unsigned short hh, ll;
            splitbf(tmp[j], hh, ll);
            ah[ks][j] = (short)hh; al[ks][j] = (short)ll;
        }
    }

    auto run = [&](const bf16x8* xh, const bf16x8* xl,
                   const unsigned short* Wh, const unsigned short* Wl,
                   const float* bias, const float* addend, const float* pmask,
                   const int act, float* out, const int ldo, const int co) {
        f32x4 acc[8];
#pragma unroll
        for (int ct = 0; ct < 8; ++ct) acc[ct] = f32x4{0.f, 0.f, 0.f, 0.f};
#pragma unroll
        for (int ks = 0; ks < KT; ++ks) {
#pragma unroll
            for (int ct = 0; ct < 8; ++ct) {
                const size_t fi = (((size_t)(ks * 8 + ct)) * 64 + lane) * 8;
                const bf16x8 bh = *(const bf16x8*)(Wh + fi);
                const bf16x8 bl = *(const bf16x8*)(Wl + fi);
                acc[ct] = __builtin_amdgcn_mfma_f32_16x16x32_bf16(xh[ks], bh, acc[ct], 0, 0, 0);
                acc[ct] = __builtin_amdgcn_mfma_f32_16x16x32_bf16(xl[ks], bh, acc[ct], 0, 0, 0);
                acc[ct] = __builtin_amdgcn_mfma_f32_16x16x32_bf16(xh[ks], bl, acc[ct], 0, 0, 0);
            }
        }
#pragma unroll
        for (int ct = 0; ct < 8; ++ct) {
            const int c = ct * 16 + (lane & 15);
            const float b = bias ? bias[c] : 0.f;
#pragma unroll
            for (int r = 0; r < 4; ++r) {
                const int row = rowbase + kg * 4 + r;
                float v = acc[ct][r] + b;
                if (addend) v += addend[(size_t)row * DD + c];
                if (pmask)  v *= pmask[(size_t)row * DD + c];
                if (act == 1) v = fmaxf(v, 0.f);
                else if (act == 2) v = 1.f / (1.f + __expf(-v));
                out[(size_t)row * ldo + co + c] = v;
            }
        }
    };

    run(ah, al, Wh0, Wl0, bias0, addend0, pmask0, act0, out0, ldo0, co0);
    if (mode == 1) {
        run(ah, al, Wh1, Wl1, bias1, nullptr, nullptr, 0, out1, ldo1, co1);
    } else if (mode == 2) {
        bf16x8 uh[KT], ul[KT];
#pragma unroll
        for (int ks = 0; ks < KT; ++ks) {
#pragma unroll
            for (int j = 0; j < 8; ++j) {
                unsigned short hh, ll;
                splitbf(araw[ks][j], hh, ll);
                uh[ks][j] = (short)hh; ul[ks][j] = (short)ll;
            }
        }
        run(uh, ul, Wh1, Wl1, bias1, nullptr, nullptr, 0, out1, ldo1, co1);
    }
}

// ---------------------------------------------------------------------------
// SPMM (CSR by dst) with fused epilogue: out = act((sum + addend) * pmask)
// ---------------------------------------------------------------------------
__launch_bounds__(256)
__global__ void spmm_k(const float* __restrict__ H,
                       const int* __restrict__ rp,
                       const int* __restrict__ ccol,
                       const float* __restrict__ cval,
                       const float* __restrict__ addend,
                       const float* __restrict__ pmask,
                       const int act,
                       float* __restrict__ out, const int ldo, const int co)
{
    const int w = (blockIdx.x * 256 + threadIdx.x) >> 6;
    if (w >= NN) return;
    const int lane = threadIdx.x & 63;
    const int s = rp[w], e = rp[w + 1];
    float ax = 0.f, ay = 0.f;
    int j = s;
    while (j < e) {
        int cnt = e - j; if (cnt > 8) cnt = 8;
        int cols[8]; float vals[8];
#pragma unroll
        for (int q = 0; q < 8; ++q) {
            if (q < cnt) { cols[q] = ccol[j + q]; vals[q] = cval[j + q]; }
        }
#pragma unroll
        for (int q = 0; q < 8; ++q) {
            if (q < cnt) {
                const float2 hv = *reinterpret_cast<const float2*>(
                    H + (size_t)cols[q] * DD + lane * 2);
                ax = fmaf(vals[q], hv.x, ax);
                ay = fmaf(vals[q], hv.y, ay);
            }
        }
        j += cnt;
    }
    if (addend) {
        const float2 t = *reinterpret_cast<const float2*>(addend + (size_t)w * DD + lane * 2);
        ax += t.x; ay += t.y;
    }
    if (pmask) {
        const float2 m = *reinterpret_cast<const float2*>(pmask + (size_t)w * DD + lane * 2);
        ax *= m.x; ay *= m.y;
    }
    if (act == 1) { ax = fmaxf(ax, 0.f); ay = fmaxf(ay, 0.f); }
    float2 o; o.x = ax; o.y = ay;
    *reinterpret_cast<float2*>(out + (size_t)w * ldo + co + lane * 2) = o;
}

// ---------------------------------------------------------------------------
// CSR build kernels (unchanged)
// ---------------------------------------------------------------------------
__global__ void hist_k(const int* __restrict__ dstI, int* __restrict__ counts) {
    const int e = blockIdx.x * 256 + threadIdx.x;
    if (e < EE) atomicAdd(&counts[dstI[e]], 1);
}

__global__ void block_sums_k(const int* __restrict__ counts, int* __restrict__ bsum) {
    __shared__ int s[256];
    const int t = threadIdx.x;
    const int i = blockIdx.x * 256 + t;
    s[t] = (i < NN) ? counts[i] : 0;
    __syncthreads();
    for (int off = 128; off > 0; off >>= 1) {
        if (t < off) s[t] += s[t + off];
        __syncthreads();
    }
    if (t == 0) bsum[blockIdx.x] = s[0];
}

__global__ void scan_bsums_k(const int* __restrict__ bsum, int* __restrict__ bpre, const int nb) {
    __shared__ int s[512];
    const int t = threadIdx.x;
    s[t] = (t < nb) ? bsum[t] : 0;
    __syncthreads();
    for (int off = 1; off < 512; off <<= 1) {
        const int tmp = (t >= off) ? s[t - off] : 0;
        __syncthreads();
        s[t] += tmp;
        __syncthreads();
    }
    if (t < nb) bpre[t] = (t == 0) ? 0 : s[t - 1];
}

__global__ void scan_final_k(const int* __restrict__ counts, const int* __restrict__ bpre,
                             int* __restrict__ rowptr, int* __restrict__ nextc) {
    __shared__ int s[256];
    const int t = threadIdx.x;
    const int i = blockIdx.x * 256 + t;
    const int v = (i < NN) ? counts[i] : 0;
    s[t] = v;
    __syncthreads();
    for (int off = 1; off < 256; off <<= 1) {
        const int tmp = (t >= off) ? s[t - off] : 0;
        __syncthreads();
        s[t] += tmp;
        __syncthreads();
    }
    const int excl = s[t] - v + bpre[blockIdx.x];
    if (i < NN) { rowptr[i] = excl; nextc[i] = excl; }
    if (i == NN - 1) rowptr[NN] = EE;
}

__global__ void scatter_k(const int* __restrict__ srcI, const int* __restrict__ dstI,
                          const float* __restrict__ ea, int* __restrict__ nextc,
                          int* __restrict__ ccol, float* __restrict__ cval) {
    const int e = blockIdx.x * 256 + threadIdx.x;
    if (e >= EE) return;
    const int d = dstI[e];
    const int p = atomicAdd(&nextc[d], 1);
    ccol[p] = srcI[e];
    cval[p] = ea[e];
}

// ---------------------------------------------------------------------------
extern "C" void kernel_launch(void* const* d_in, const int* in_sizes, int n_in,
                              void* d_out, int out_size, void* d_ws, size_t ws_size,
                              hipStream_t stream)
{
    const float* x_in0      = (const float*)d_in[0];
    const float* edge_attr  = (const float*)d_in[1];
    const int*   edge_index = (const int*)d_in[2];
    const float* conv_w     = (const float*)d_in[3];
    const float* conv_lin_w = (const float*)d_in[4];
    const float* l1_w       = (const float*)d_in[5];
    const float* l1_b       = (const float*)d_in[6];
    const float* l2_w       = (const float*)d_in[7];
    const float* l2_b       = (const float*)d_in[8];
    const float* mlp1_w     = (const float*)d_in[9];
    const float* mlp1_b     = (const float*)d_in[10];
    const float* mlp2_w     = (const float*)d_in[11];
    const float* mlp2_b     = (const float*)d_in[12];
    const float* post1_w    = (const float*)d_in[13];
    const float* post1_b    = (const float*)d_in[14];
    const float* post2_w    = (const float*)d_in[15];
    const float* post2_b    = (const float*)d_in[16];

    const int* srcI = edge_index;
    const int* dstI = edge_index + EE;

    float* x_ws = (float*)d_out;   // x ping buffer (see round-0 notes)

    // ws layout (16B-aligned chunks first)
    float* maskbuf = (float*)d_ws;                       // [NN][DD]
    float* h       = maskbuf + (size_t)NN * DD;          // [NN][DD]
    float* cat     = h + (size_t)NN * DD;                // [NN][2*DD]
    unsigned short* Wh_all = (unsigned short*)(cat + (size_t)NN * 2 * DD); // 376832
    unsigned short* Wl_all = Wh_all + 376832;            // 376832
    float* cval    = (float*)(Wl_all + 376832);          // [EE]
    int*   ccol    = (int*)(cval + EE);                  // [EE]
    int*   rowptr  = ccol + EE;                          // [NN+1]
    int*   nextc   = rowptr + (NN + 1);                  // [NN]
    int*   counts  = nextc + NN;                         // [NN]
    int*   bsum    = counts + NN;                        // [512]
    int*   bpre    = bsum + 512;                         // [512]

    // ---- W fragment pre-pack + CSR build ----
    wfrag_k<<<92, 256, 0, stream>>>(l1_w, l2_w, mlp1_w, mlp2_w, conv_w, conv_lin_w,
                                    post1_w, post2_w, Wh_all, Wl_all);
    hipMemsetAsync(counts, 0, NN * sizeof(int), stream);
    hist_k      <<<(EE + 255) / 256, 256, 0, stream>>>(dstI, counts);
    block_sums_k<<<NB_SCAN, 256, 0, stream>>>(counts, bsum);
    scan_bsums_k<<<1, 512, 0, stream>>>(bsum, bpre, NB_SCAN);
    scan_final_k<<<NB_SCAN, 256, 0, stream>>>(counts, bpre, rowptr, nextc);
    scatter_k   <<<(EE + 255) / 256, 256, 0, stream>>>(srcI, dstI, edge_attr, nextc, ccol, cval);

    const int GG = (6250 + 3) / 4;        // 1563 blocks, 4 waves each, 16 rows/wave
    const int SPMM_GRID = NN * 64 / 256;  // 25000

    // frag element offsets
    const size_t F_L1 = 0, F_L2 = 49152, F_M1 = 98304, F_M2 = 196608;
    const size_t F_CV = 245760, F_CL = 294912, F_P1 = 344064, F_P2 = 360448;

    for (int i = 0; i < 3; ++i) {
        const float* xc = (i == 0) ? x_in0 : x_ws;
        const float* pm = (i == 0) ? nullptr : maskbuf;
        const size_t o128 = (size_t)i * 16384, o256 = (size_t)i * 32768;
        // dual: h = xm@l1+b ; cat[:,128:] = xm@l2+b
        gemm_mfma<4><<<GG, 256, 0, stream>>>(xc, pm, 0,
            Wh_all + F_L1 + o128, Wl_all + F_L1 + o128, l1_b + (size_t)i * DD,
            nullptr, nullptr, 0, h, DD, 0,
            1, Wh_all + F_L2 + o128, Wl_all + F_L2 + o128, l2_b + (size_t)i * DD,
            cat, 2 * DD, DD);
        // cat[:,0:128] = agg(h)
        spmm_k<<<SPMM_GRID, 256, 0, stream>>>(h, rowptr, ccol, cval,
                                              nullptr, nullptr, 0, cat, 2 * DD, 0);
        // hh = relu(relu(cat)@mlp1+b) -> h
        gemm_mfma<8><<<GG, 256, 0, stream>>>(cat, nullptr, 1,
            Wh_all + F_M1 + o256, Wl_all + F_M1 + o256, mlp1_b + (size_t)i * DD,
            nullptr, nullptr, 1, h, DD, 0,
            0, nullptr, nullptr, nullptr, nullptr, 0, 0);
        // mask = sigmoid(hh@mlp2+b) -> maskbuf
        gemm_mfma<4><<<GG, 256, 0, stream>>>(h, nullptr, 0,
            Wh_all + F_M2 + o128, Wl_all + F_M2 + o128, mlp2_b + (size_t)i * DD,
            nullptr, nullptr, 2, maskbuf, DD, 0,
            0, nullptr, nullptr, nullptr, nullptr, 0, 0);
        // dual mode2: h2 = (x*mask)@convw -> h ; t = x@convlin -> cat (as [NN][128])
        gemm_mfma<4><<<GG, 256, 0, stream>>>(xc, maskbuf, 0,
            Wh_all + F_CV + o128, Wl_all + F_CV + o128, nullptr,
            nullptr, nullptr, 0, h, DD, 0,
            2, Wh_all + F_CL + o128, Wl_all + F_CL + o128, nullptr,
            cat, DD, 0);
        // x = relu((agg(h2) + t) * mask) -> x_ws
        spmm_k<<<SPMM_GRID, 256, 0, stream>>>(h, rowptr, ccol, cval,
                                              cat, maskbuf, 1, x_ws, DD, 0);
    }
    // y1 = relu(x@post1+b) -> h
    gemm_mfma<4><<<GG, 256, 0, stream>>>(x_ws, nullptr, 0,
        Wh_all + F_P1, Wl_all + F_P1, post1_b, nullptr, nullptr, 1, h, DD, 0,
        0, nullptr, nullptr, nullptr, nullptr, 0, 0);
    // out = y1@post2+b -> d_out
    gemm_mfma<4><<<GG, 256, 0, stream>>>(h, nullptr, 0,
        Wh_all + F_P2, Wl_all + F_P2, post2_b, nullptr, nullptr, 0, (float*)d_out, DD, 0,
        0, nullptr, nullptr, nullptr, nullptr, 0, 0);

    (void)in_sizes; (void)n_in; (void)out_size; (void)ws_size;
}

// Round 4
// 1667.333 us; speedup vs baseline: 1.1770x; 1.0011x over previous
//
#include <hip/hip_runtime.h>
#include <math.h>

#define NN 100000
#define EE 640000
#define DD 128
#define NB_SCAN ((NN + 255) / 256)   // 391

typedef __attribute__((ext_vector_type(8))) short bf16x8;
typedef __attribute__((ext_vector_type(4))) float f32x4;

static __device__ __forceinline__ float4 ld4(const float* p) {
    return *reinterpret_cast<const float4*>(p);
}

// split fp32 a into hi+lo bf16 (both RNE): a ~= hi + lo
static __device__ __forceinline__ void splitbf(float a, unsigned short& hi, unsigned short& lo) {
    unsigned u = __float_as_uint(a);
    unsigned hr = (u + 0x7FFFu + ((u >> 16) & 1u)) >> 16;
    float hf = __uint_as_float(hr << 16);
    float l = a - hf;
    unsigned ul = __float_as_uint(l);
    unsigned lr = (ul + 0x7FFFu + ((ul >> 16) & 1u)) >> 16;
    hi = (unsigned short)hr; lo = (unsigned short)lr;
}

// ---------------------------------------------------------------------------
// W-fragment pre-pack (unchanged layout):
//   frag[((ks*8+ct)*64+lane)*8 + r] = W[ks*32 + (lane>>4)*8 + r][ct*16 + (lane&15)]
// ---------------------------------------------------------------------------
__global__ void wfrag_k(const float* __restrict__ l1w, const float* __restrict__ l2w,
                        const float* __restrict__ mlp1w, const float* __restrict__ mlp2w,
                        const float* __restrict__ convw, const float* __restrict__ convlinw,
                        const float* __restrict__ post1w, const float* __restrict__ post2w,
                        unsigned short* __restrict__ Wh, unsigned short* __restrict__ Wl)
{
    const int b = blockIdx.x;
    const float* W; int slice; size_t fbase; int K;
    if (b < 12)      { W = l1w;      slice = b;      fbase = 0;      K = 128; }
    else if (b < 24) { W = l2w;      slice = b - 12; fbase = 49152;  K = 128; }
    else if (b < 48) { W = mlp1w;    slice = b - 24; fbase = 98304;  K = 256; }
    else if (b < 60) { W = mlp2w;    slice = b - 48; fbase = 196608; K = 128; }
    else if (b < 72) { W = convw;    slice = b - 60; fbase = 245760; K = 128; }
    else if (b < 84) { W = convlinw; slice = b - 72; fbase = 294912; K = 128; }
    else if (b < 88) { W = post1w;   slice = b - 84; fbase = 344064; K = 128; }
    else             { W = post2w;   slice = b - 88; fbase = 360448; K = 128; }
    const int kslices = K / 32;
    const int mat = slice / kslices;
    const int ks  = slice % kslices;
    const float* Wm = W + (size_t)mat * K * DD;
    const size_t outb = fbase + (size_t)mat * K * DD + (size_t)ks * 4096;
    const int t = threadIdx.x;
#pragma unroll
    for (int e = 0; e < 16; ++e) {
        const int f = t * 16 + e;
        const int r = f & 7, lane = (f >> 3) & 63, ct = f >> 9;
        const int krow = ks * 32 + (lane >> 4) * 8 + r;
        const int col  = ct * 16 + (lane & 15);
        unsigned short hh, ll;
        splitbf(Wm[(size_t)krow * DD + col], hh, ll);
        Wh[outb + f] = hh; Wl[outb + f] = ll;
    }
}

// ---------------------------------------------------------------------------
// MFMA GEMM v2: wave = 32 rows x 128 cols (2 m-tiles), block = 4 waves = 128
// rows.  W fragments staged in 32KB LDS (2 k-slices hi+lo per stage), shared
// by the block; B reads are conflict-free ds_read_b128.  No early returns
// (tail rows clamped / stores predicated) so barriers are uniform.
// ---------------------------------------------------------------------------
template<int KT>   // K = KT*32
__launch_bounds__(256)
__global__ void gemm_mfma2(const float* __restrict__ A,
                           const float* __restrict__ Amask, const int reluA,
                           const unsigned short* __restrict__ Wh,
                           const unsigned short* __restrict__ Wl,
                           const float* __restrict__ bias,
                           const float* __restrict__ addend,
                           const float* __restrict__ pmask,
                           const int act,
                           float* __restrict__ out, const int ldo, const int co)
{
    __shared__ __align__(16) unsigned short Bs[16384];  // hi [0,8192), lo [8192,16384)

    const int t    = threadIdx.x;
    const int lane = t & 63;
    const int w    = t >> 6;
    const int kg   = lane >> 4;     // k-group 0..3
    const int c16  = lane & 15;
    const int rb   = blockIdx.x * 128 + w * 32;

    int ra[2];
#pragma unroll
    for (int mt = 0; mt < 2; ++mt) {
        int r = rb + mt * 16 + c16;
        ra[mt] = (r < NN) ? r : (NN - 1);
    }

    f32x4 acc[2][8];
#pragma unroll
    for (int mt = 0; mt < 2; ++mt)
#pragma unroll
        for (int ct = 0; ct < 8; ++ct) acc[mt][ct] = f32x4{0.f, 0.f, 0.f, 0.f};

#pragma unroll
    for (int stage = 0; stage < KT / 2; ++stage) {
        // ---- A: load raw (+mask, relu), split to bf16 hi/lo — all pre-barrier
        bf16x8 ah[2][2], al[2][2];   // [slice][mtile]
#pragma unroll
        for (int s = 0; s < 2; ++s) {
            const int ks = stage * 2 + s;
#pragma unroll
            for (int mt = 0; mt < 2; ++mt) {
                const float* ap = A + (size_t)ra[mt] * (KT * 32) + ks * 32 + kg * 8;
                const float4 v0 = ld4(ap), v1 = ld4(ap + 4);
                float tmp[8] = {v0.x, v0.y, v0.z, v0.w, v1.x, v1.y, v1.z, v1.w};
                if (Amask) {   // only K==128 paths use mask (stride DD)
                    const float* mp = Amask + (size_t)ra[mt] * DD + ks * 32 + kg * 8;
                    const float4 m0 = ld4(mp), m1 = ld4(mp + 4);
                    tmp[0] *= m0.x; tmp[1] *= m0.y; tmp[2] *= m0.z; tmp[3] *= m0.w;
                    tmp[4] *= m1.x; tmp[5] *= m1.y; tmp[6] *= m1.z; tmp[7] *= m1.w;
                }
                if (reluA) {
#pragma unroll
                    for (int j = 0; j < 8; ++j) tmp[j] = fmaxf(tmp[j], 0.f);
                }
#pragma unroll
                for (int j = 0; j < 8; ++j) {
                    unsigned short hh, ll;
                    splitbf(tmp[j], hh, ll);
                    ah[s][mt][j] = (short)hh; al[s][mt][j] = (short)ll;
                }
            }
        }

        // ---- stage 2 k-slices of W (hi+lo) into LDS ----
        if (stage) __syncthreads();          // prior stage's reads complete
        {
            const unsigned short* gh = Wh + (size_t)stage * 8192;
            const unsigned short* gl = Wl + (size_t)stage * 8192;
#pragma unroll
            for (int i = 0; i < 4; ++i) {
                const int idx = i * 2048 + t * 8;
                *(uint4*)&Bs[idx]        = *(const uint4*)&gh[idx];
                *(uint4*)&Bs[8192 + idx] = *(const uint4*)&gl[idx];
            }
        }
        __syncthreads();

        // ---- compute: 2 slices x 8 col-tiles x (2 mt x 3 mfma) ----
#pragma unroll
        for (int s = 0; s < 2; ++s) {
#pragma unroll
            for (int ct = 0; ct < 8; ++ct) {
                const int fo = ((s * 8 + ct) * 64 + lane) * 8;
                const bf16x8 bh = *(const bf16x8*)&Bs[fo];
                const bf16x8 bl = *(const bf16x8*)&Bs[8192 + fo];
#pragma unroll
                for (int mt = 0; mt < 2; ++mt) {
                    acc[mt][ct] = __builtin_amdgcn_mfma_f32_16x16x32_bf16(ah[s][mt], bh, acc[mt][ct], 0, 0, 0);
                    acc[mt][ct] = __builtin_amdgcn_mfma_f32_16x16x32_bf16(al[s][mt], bh, acc[mt][ct], 0, 0, 0);
                    acc[mt][ct] = __builtin_amdgcn_mfma_f32_16x16x32_bf16(ah[s][mt], bl, acc[mt][ct], 0, 0, 0);
                }
            }
        }
    }

    // ---- epilogue ----
#pragma unroll
    for (int ct = 0; ct < 8; ++ct) {
        const int c = ct * 16 + c16;
        const float b = bias ? bias[c] : 0.f;
#pragma unroll
        for (int mt = 0; mt < 2; ++mt) {
#pragma unroll
            for (int r = 0; r < 4; ++r) {
                const int row = rb + mt * 16 + kg * 4 + r;
                if (row < NN) {
                    float v = acc[mt][ct][r] + b;
                    if (addend) v += addend[(size_t)row * DD + c];
                    if (pmask)  v *= pmask[(size_t)row * DD + c];
                    if (act == 1) v = fmaxf(v, 0.f);
                    else if (act == 2) v = 1.f / (1.f + __expf(-v));
                    out[(size_t)row * ldo + co + c] = v;
                }
            }
        }
    }
}

// ---------------------------------------------------------------------------
// SPMM (CSR by dst) with fused epilogue: out = act((sum + addend) * pmask)
// ---------------------------------------------------------------------------
__launch_bounds__(256)
__global__ void spmm_k(const float* __restrict__ H,
                       const int* __restrict__ rp,
                       const int* __restrict__ ccol,
                       const float* __restrict__ cval,
                       const float* __restrict__ addend,
                       const float* __restrict__ pmask,
                       const int act,
                       float* __restrict__ out, const int ldo, const int co)
{
    const int w = (blockIdx.x * 256 + threadIdx.x) >> 6;
    if (w >= NN) return;
    const int lane = threadIdx.x & 63;
    const int s = rp[w], e = rp[w + 1];
    float ax = 0.f, ay = 0.f;
    int j = s;
    while (j < e) {
        int cnt = e - j; if (cnt > 8) cnt = 8;
        int cols[8]; float vals[8];
#pragma unroll
        for (int q = 0; q < 8; ++q) {
            if (q < cnt) { cols[q] = ccol[j + q]; vals[q] = cval[j + q]; }
        }
#pragma unroll
        for (int q = 0; q < 8; ++q) {
            if (q < cnt) {
                const float2 hv = *reinterpret_cast<const float2*>(
                    H + (size_t)cols[q] * DD + lane * 2);
                ax = fmaf(vals[q], hv.x, ax);
                ay = fmaf(vals[q], hv.y, ay);
            }
        }
        j += cnt;
    }
    if (addend) {
        const float2 tt = *reinterpret_cast<const float2*>(addend + (size_t)w * DD + lane * 2);
        ax += tt.x; ay += tt.y;
    }
    if (pmask) {
        const float2 m = *reinterpret_cast<const float2*>(pmask + (size_t)w * DD + lane * 2);
        ax *= m.x; ay *= m.y;
    }
    if (act == 1) { ax = fmaxf(ax, 0.f); ay = fmaxf(ay, 0.f); }
    float2 o; o.x = ax; o.y = ay;
    *reinterpret_cast<float2*>(out + (size_t)w * ldo + co + lane * 2) = o;
}

// ---------------------------------------------------------------------------
// CSR build kernels (unchanged)
// ---------------------------------------------------------------------------
__global__ void hist_k(const int* __restrict__ dstI, int* __restrict__ counts) {
    const int e = blockIdx.x * 256 + threadIdx.x;
    if (e < EE) atomicAdd(&counts[dstI[e]], 1);
}

__global__ void block_sums_k(const int* __restrict__ counts, int* __restrict__ bsum) {
    __shared__ int s[256];
    const int t = threadIdx.x;
    const int i = blockIdx.x * 256 + t;
    s[t] = (i < NN) ? counts[i] : 0;
    __syncthreads();
    for (int off = 128; off > 0; off >>= 1) {
        if (t < off) s[t] += s[t + off];
        __syncthreads();
    }
    if (t == 0) bsum[blockIdx.x] = s[0];
}

__global__ void scan_bsums_k(const int* __restrict__ bsum, int* __restrict__ bpre, const int nb) {
    __shared__ int s[512];
    const int t = threadIdx.x;
    s[t] = (t < nb) ? bsum[t] : 0;
    __syncthreads();
    for (int off = 1; off < 512; off <<= 1) {
        const int tmp = (t >= off) ? s[t - off] : 0;
        __syncthreads();
        s[t] += tmp;
        __syncthreads();
    }
    if (t < nb) bpre[t] = (t == 0) ? 0 : s[t - 1];
}

__global__ void scan_final_k(const int* __restrict__ counts, const int* __restrict__ bpre,
                             int* __restrict__ rowptr, int* __restrict__ nextc) {
    __shared__ int s[256];
    const int t = threadIdx.x;
    const int i = blockIdx.x * 256 + t;
    const int v = (i < NN) ? counts[i] : 0;
    s[t] = v;
    __syncthreads();
    for (int off = 1; off < 256; off <<= 1) {
        const int tmp = (t >= off) ? s[t - off] : 0;
        __syncthreads();
        s[t] += tmp;
        __syncthreads();
    }
    const int excl = s[t] - v + bpre[blockIdx.x];
    if (i < NN) { rowptr[i] = excl; nextc[i] = excl; }
    if (i == NN - 1) rowptr[NN] = EE;
}

__global__ void scatter_k(const int* __restrict__ srcI, const int* __restrict__ dstI,
                          const float* __restrict__ ea, int* __restrict__ nextc,
                          int* __restrict__ ccol, float* __restrict__ cval) {
    const int e = blockIdx.x * 256 + threadIdx.x;
    if (e >= EE) return;
    const int d = dstI[e];
    const int p = atomicAdd(&nextc[d], 1);
    ccol[p] = srcI[e];
    cval[p] = ea[e];
}

// ---------------------------------------------------------------------------
extern "C" void kernel_launch(void* const* d_in, const int* in_sizes, int n_in,
                              void* d_out, int out_size, void* d_ws, size_t ws_size,
                              hipStream_t stream)
{
    const float* x_in0      = (const float*)d_in[0];
    const float* edge_attr  = (const float*)d_in[1];
    const int*   edge_index = (const int*)d_in[2];
    const float* conv_w     = (const float*)d_in[3];
    const float* conv_lin_w = (const float*)d_in[4];
    const float* l1_w       = (const float*)d_in[5];
    const float* l1_b       = (const float*)d_in[6];
    const float* l2_w       = (const float*)d_in[7];
    const float* l2_b       = (const float*)d_in[8];
    const float* mlp1_w     = (const float*)d_in[9];
    const float* mlp1_b     = (const float*)d_in[10];
    const float* mlp2_w     = (const float*)d_in[11];
    const float* mlp2_b     = (const float*)d_in[12];
    const float* post1_w    = (const float*)d_in[13];
    const float* post1_b    = (const float*)d_in[14];
    const float* post2_w    = (const float*)d_in[15];
    const float* post2_b    = (const float*)d_in[16];

    const int* srcI = edge_index;
    const int* dstI = edge_index + EE;

    float* x_ws = (float*)d_out;   // x ping buffer

    float* maskbuf = (float*)d_ws;                       // [NN][DD]
    float* h       = maskbuf + (size_t)NN * DD;          // [NN][DD]
    float* cat     = h + (size_t)NN * DD;                // [NN][2*DD]
    unsigned short* Wh_all = (unsigned short*)(cat + (size_t)NN * 2 * DD); // 376832
    unsigned short* Wl_all = Wh_all + 376832;            // 376832
    float* cval    = (float*)(Wl_all + 376832);          // [EE]
    int*   ccol    = (int*)(cval + EE);                  // [EE]
    int*   rowptr  = ccol + EE;                          // [NN+1]
    int*   nextc   = rowptr + (NN + 1);                  // [NN]
    int*   counts  = nextc + NN;                         // [NN]
    int*   bsum    = counts + NN;                        // [512]
    int*   bpre    = bsum + 512;                         // [512]

    wfrag_k<<<92, 256, 0, stream>>>(l1_w, l2_w, mlp1_w, mlp2_w, conv_w, conv_lin_w,
                                    post1_w, post2_w, Wh_all, Wl_all);
    hipMemsetAsync(counts, 0, NN * sizeof(int), stream);
    hist_k      <<<(EE + 255) / 256, 256, 0, stream>>>(dstI, counts);
    block_sums_k<<<NB_SCAN, 256, 0, stream>>>(counts, bsum);
    scan_bsums_k<<<1, 512, 0, stream>>>(bsum, bpre, NB_SCAN);
    scan_final_k<<<NB_SCAN, 256, 0, stream>>>(counts, bpre, rowptr, nextc);
    scatter_k   <<<(EE + 255) / 256, 256, 0, stream>>>(srcI, dstI, edge_attr, nextc, ccol, cval);

    const int GG = (NN + 127) / 128;      // 782 blocks (128 rows each)
    const int SPMM_GRID = NN * 64 / 256;  // 25000

    const size_t F_L1 = 0, F_L2 = 49152, F_M1 = 98304, F_M2 = 196608;
    const size_t F_CV = 245760, F_CL = 294912, F_P1 = 344064, F_P2 = 360448;

    for (int i = 0; i < 3; ++i) {
        const float* xc = (i == 0) ? x_in0 : x_ws;
        const float* pm = (i == 0) ? nullptr : maskbuf;
        const size_t o128 = (size_t)i * 16384, o256 = (size_t)i * 32768;
        // h = xm @ l1 + b
        gemm_mfma2<4><<<GG, 256, 0, stream>>>(xc, pm, 0,
            Wh_all + F_L1 + o128, Wl_all + F_L1 + o128, l1_b + (size_t)i * DD,
            nullptr, nullptr, 0, h, DD, 0);
        // cat[:,128:] = xm @ l2 + b
        gemm_mfma2<4><<<GG, 256, 0, stream>>>(xc, pm, 0,
            Wh_all + F_L2 + o128, Wl_all + F_L2 + o128, l2_b + (size_t)i * DD,
            nullptr, nullptr, 0, cat, 2 * DD, DD);
        // cat[:,0:128] = agg(h)
        spmm_k<<<SPMM_GRID, 256, 0, stream>>>(h, rowptr, ccol, cval,
                                              nullptr, nullptr, 0, cat, 2 * DD, 0);
        // h = relu(relu(cat) @ mlp1 + b)
        gemm_mfma2<8><<<GG, 256, 0, stream>>>(cat, nullptr, 1,
            Wh_all + F_M1 + o256, Wl_all + F_M1 + o256, mlp1_b + (size_t)i * DD,
            nullptr, nullptr, 1, h, DD, 0);
        // mask = sigmoid(h @ mlp2 + b)
        gemm_mfma2<4><<<GG, 256, 0, stream>>>(h, nullptr, 0,
            Wh_all + F_M2 + o128, Wl_all + F_M2 + o128, mlp2_b + (size_t)i * DD,
            nullptr, nullptr, 2, maskbuf, DD, 0);
        // h2 = (x*mask) @ conv_w  -> h   (h free after mlp2)
        gemm_mfma2<4><<<GG, 256, 0, stream>>>(xc, maskbuf, 0,
            Wh_all + F_CV + o128, Wl_all + F_CV + o128, nullptr,
            nullptr, nullptr, 0, h, DD, 0);
        // t = x @ conv_lin -> cat (as [NN][128]; cat free after mlp1)
        gemm_mfma2<4><<<GG, 256, 0, stream>>>(xc, nullptr, 0,
            Wh_all + F_CL + o128, Wl_all + F_CL + o128, nullptr,
            nullptr, nullptr, 0, cat, DD, 0);
        // x = relu((agg(h2) + t) * mask) -> x_ws
        spmm_k<<<SPMM_GRID, 256, 0, stream>>>(h, rowptr, ccol, cval,
                                              cat, maskbuf, 1, x_ws, DD, 0);
    }
    // y1 = relu(x @ post1 + b) -> h
    gemm_mfma2<4><<<GG, 256, 0, stream>>>(x_ws, nullptr, 0,
        Wh_all + F_P1, Wl_all + F_P1, post1_b, nullptr, nullptr, 1, h, DD, 0);
    // out = y1 @ post2 + b -> d_out
    gemm_mfma2<4><<<GG, 256, 0, stream>>>(h, nullptr, 0,
        Wh_all + F_P2, Wl_all + F_P2, post2_b, nullptr, nullptr, 0, (float*)d_out, DD, 0);

    (void)in_sizes; (void)n_in; (void)out_size; (void)ws_size;
}

// Round 5
// 1187.129 us; speedup vs baseline: 1.6531x; 1.4045x over previous
//
#include <hip/hip_runtime.h>
#include <math.h>

#define NN 100000
#define EE 640000
#define DD 128
#define NB_SCAN ((NN + 255) / 256)   // 391

typedef __attribute__((ext_vector_type(8))) short bf16x8;
typedef __attribute__((ext_vector_type(4))) float f32x4;

static __device__ __forceinline__ float4 ld4(const float* p) {
    return *reinterpret_cast<const float4*>(p);
}

// fp32 -> bf16 RNE
static __device__ __forceinline__ unsigned short f2bf(float x) {
    unsigned u = __float_as_uint(x);
    return (unsigned short)((u + 0x7FFFu + ((u >> 16) & 1u)) >> 16);
}

// split fp32 a into hi+lo bf16 (both RNE): a ~= hi + lo
static __device__ __forceinline__ void splitbf(float a, short& hi, short& lo) {
    unsigned u = __float_as_uint(a);
    unsigned hr = (u + 0x7FFFu + ((u >> 16) & 1u)) >> 16;
    float hf = __uint_as_float(hr << 16);
    float l = a - hf;
    unsigned ul = __float_as_uint(l);
    unsigned lr = (ul + 0x7FFFu + ((ul >> 16) & 1u)) >> 16;
    hi = (short)hr; lo = (short)lr;
}

// ---------------------------------------------------------------------------
// W-fragment pre-pack (unchanged layout):
//   frag[((ks*8+ct)*64+lane)*8 + r] = W[ks*32 + (lane>>4)*8 + r][ct*16 + (lane&15)]
// ---------------------------------------------------------------------------
__global__ void wfrag_k(const float* __restrict__ l1w, const float* __restrict__ l2w,
                        const float* __restrict__ mlp1w, const float* __restrict__ mlp2w,
                        const float* __restrict__ convw, const float* __restrict__ convlinw,
                        const float* __restrict__ post1w, const float* __restrict__ post2w,
                        unsigned short* __restrict__ Wh, unsigned short* __restrict__ Wl)
{
    const int b = blockIdx.x;
    const float* W; int slice; size_t fbase; int K;
    if (b < 12)      { W = l1w;      slice = b;      fbase = 0;      K = 128; }
    else if (b < 24) { W = l2w;      slice = b - 12; fbase = 49152;  K = 128; }
    else if (b < 48) { W = mlp1w;    slice = b - 24; fbase = 98304;  K = 256; }
    else if (b < 60) { W = mlp2w;    slice = b - 48; fbase = 196608; K = 128; }
    else if (b < 72) { W = convw;    slice = b - 60; fbase = 245760; K = 128; }
    else if (b < 84) { W = convlinw; slice = b - 72; fbase = 294912; K = 128; }
    else if (b < 88) { W = post1w;   slice = b - 84; fbase = 344064; K = 128; }
    else             { W = post2w;   slice = b - 88; fbase = 360448; K = 128; }
    const int kslices = K / 32;
    const int mat = slice / kslices;
    const int ks  = slice % kslices;
    const float* Wm = W + (size_t)mat * K * DD;
    const size_t outb = fbase + (size_t)mat * K * DD + (size_t)ks * 4096;
    const int t = threadIdx.x;
#pragma unroll
    for (int e = 0; e < 16; ++e) {
        const int f = t * 16 + e;
        const int r = f & 7, lane = (f >> 3) & 63, ct = f >> 9;
        const int krow = ks * 32 + (lane >> 4) * 8 + r;
        const int col  = ct * 16 + (lane & 15);
        short hh, ll;
        splitbf(Wm[(size_t)krow * DD + col], hh, ll);
        Wh[outb + f] = (unsigned short)hh; Wl[outb + f] = (unsigned short)ll;
    }
}

// ---------------------------------------------------------------------------
// GEMM v3, fp32 A: wave = 16 rows x 128 cols, block = 4 waves = 64 rows.
// Full A kept in registers (split bf16 hi/lo); W staged 16KB/stage in LDS.
// DUAL: second output reuses A registers (RAW1: un-masked A for out1).
// obf: write bf16 (ushort) output instead of fp32.
// ---------------------------------------------------------------------------
template<int KT, int DUAL, int RAW1, int MINW>
__launch_bounds__(256, MINW)
__global__ void gemm_f32A(const float* __restrict__ A,
                          const float* __restrict__ Amask,
                          const unsigned short* __restrict__ Wh0,
                          const unsigned short* __restrict__ Wl0,
                          const float* __restrict__ bias0, const int act0, const int obf0,
                          void* __restrict__ out0, const int ldo0, const int co0,
                          const unsigned short* __restrict__ Wh1,
                          const unsigned short* __restrict__ Wl1,
                          const float* __restrict__ bias1, const int obf1,
                          void* __restrict__ out1, const int ldo1, const int co1)
{
    __shared__ __align__(16) unsigned short Bs[16384];
    const int t = threadIdx.x, lane = t & 63, w = t >> 6;
    const int kg = lane >> 4, c16 = lane & 15;
    const int rb = blockIdx.x * 64 + w * 16;
    int ra = rb + c16; if (ra >= NN) ra = NN - 1;

    bf16x8 ah[KT], al[KT];
    bf16x8 uh[RAW1 ? KT : 1], ul[RAW1 ? KT : 1];
#pragma unroll
    for (int ks = 0; ks < KT; ++ks) {
        const float* ap = A + (size_t)ra * (KT * 32) + ks * 32 + kg * 8;
        const float4 v0 = ld4(ap), v1 = ld4(ap + 4);
        float tmp[8] = {v0.x, v0.y, v0.z, v0.w, v1.x, v1.y, v1.z, v1.w};
        if (RAW1) {
#pragma unroll
            for (int j = 0; j < 8; ++j) { short hh, ll; splitbf(tmp[j], hh, ll); uh[ks][j] = hh; ul[ks][j] = ll; }
        }
        if (Amask) {
            const float* mp = Amask + (size_t)ra * DD + ks * 32 + kg * 8;
            const float4 m0 = ld4(mp), m1 = ld4(mp + 4);
            tmp[0] *= m0.x; tmp[1] *= m0.y; tmp[2] *= m0.z; tmp[3] *= m0.w;
            tmp[4] *= m1.x; tmp[5] *= m1.y; tmp[6] *= m1.z; tmp[7] *= m1.w;
        }
#pragma unroll
        for (int j = 0; j < 8; ++j) { short hh, ll; splitbf(tmp[j], hh, ll); ah[ks][j] = hh; al[ks][j] = ll; }
    }

    auto pass = [&](const unsigned short* Wh, const unsigned short* Wl,
                    const bf16x8* xh, const bf16x8* xl,
                    const float* bias, const int act, const int obf,
                    void* out, const int ldo, const int co, const bool first) {
        f32x4 acc[8];
#pragma unroll
        for (int ct = 0; ct < 8; ++ct) acc[ct] = f32x4{0.f, 0.f, 0.f, 0.f};
#pragma unroll
        for (int st = 0; st < KT / 2; ++st) {
            if (!(first && st == 0)) __syncthreads();
#pragma unroll
            for (int i = 0; i < 4; ++i) {
                const int idx = i * 2048 + t * 8;
                *(uint4*)&Bs[idx]        = *(const uint4*)&Wh[(size_t)st * 8192 + idx];
                *(uint4*)&Bs[8192 + idx] = *(const uint4*)&Wl[(size_t)st * 8192 + idx];
            }
            __syncthreads();
#pragma unroll
            for (int s = 0; s < 2; ++s) {
                const int ks = st * 2 + s;
#pragma unroll
                for (int ct = 0; ct < 8; ++ct) {
                    const int fo = ((s * 8 + ct) * 64 + lane) * 8;
                    const bf16x8 bh = *(const bf16x8*)&Bs[fo];
                    const bf16x8 bl = *(const bf16x8*)&Bs[8192 + fo];
                    acc[ct] = __builtin_amdgcn_mfma_f32_16x16x32_bf16(xh[ks], bh, acc[ct], 0, 0, 0);
                    acc[ct] = __builtin_amdgcn_mfma_f32_16x16x32_bf16(xl[ks], bh, acc[ct], 0, 0, 0);
                    acc[ct] = __builtin_amdgcn_mfma_f32_16x16x32_bf16(xh[ks], bl, acc[ct], 0, 0, 0);
                }
            }
        }
#pragma unroll
        for (int ct = 0; ct < 8; ++ct) {
            const int c = ct * 16 + c16;
            const float b = bias ? bias[c] : 0.f;
#pragma unroll
            for (int r = 0; r < 4; ++r) {
                const int row = rb + kg * 4 + r;
                if (row < NN) {
                    float v = acc[ct][r] + b;
                    if (act == 1) v = fmaxf(v, 0.f);
                    if (obf) ((unsigned short*)out)[(size_t)row * ldo + co + c] = f2bf(v);
                    else     ((float*)out)[(size_t)row * ldo + co + c] = v;
                }
            }
        }
    };

    pass(Wh0, Wl0, ah, al, bias0, act0, obf0, out0, ldo0, co0, true);
    if (DUAL)
        pass(Wh1, Wl1, RAW1 ? uh : ah, RAW1 ? ul : al, bias1, 0, obf1, out1, ldo1, co1, false);
}

// ---------------------------------------------------------------------------
// GEMM v3, bf16 A (exact: lo(A)=0 -> 2 MFMAs per k-slice).
// ---------------------------------------------------------------------------
template<int KT, int MINW>
__launch_bounds__(256, MINW)
__global__ void gemm_bf16A(const unsigned short* __restrict__ A, const int reluA,
                           const unsigned short* __restrict__ Wh,
                           const unsigned short* __restrict__ Wl,
                           const float* __restrict__ bias, const int act, const int obf,
                           void* __restrict__ out, const int ldo, const int co)
{
    __shared__ __align__(16) unsigned short Bs[16384];
    const int t = threadIdx.x, lane = t & 63, w = t >> 6;
    const int kg = lane >> 4, c16 = lane & 15;
    const int rb = blockIdx.x * 64 + w * 16;
    int ra = rb + c16; if (ra >= NN) ra = NN - 1;

    bf16x8 ah[KT];
#pragma unroll
    for (int ks = 0; ks < KT; ++ks) {
        bf16x8 av = *(const bf16x8*)(A + (size_t)ra * (KT * 32) + ks * 32 + kg * 8);
        if (reluA) {
#pragma unroll
            for (int j = 0; j < 8; ++j) av[j] = (av[j] < 0) ? (short)0 : av[j];
        }
        ah[ks] = av;
    }

    f32x4 acc[8];
#pragma unroll
    for (int ct = 0; ct < 8; ++ct) acc[ct] = f32x4{0.f, 0.f, 0.f, 0.f};
#pragma unroll
    for (int st = 0; st < KT / 2; ++st) {
        if (st) __syncthreads();
#pragma unroll
        for (int i = 0; i < 4; ++i) {
            const int idx = i * 2048 + t * 8;
            *(uint4*)&Bs[idx]        = *(const uint4*)&Wh[(size_t)st * 8192 + idx];
            *(uint4*)&Bs[8192 + idx] = *(const uint4*)&Wl[(size_t)st * 8192 + idx];
        }
        __syncthreads();
#pragma unroll
        for (int s = 0; s < 2; ++s) {
            const int ks = st * 2 + s;
#pragma unroll
            for (int ct = 0; ct < 8; ++ct) {
                const int fo = ((s * 8 + ct) * 64 + lane) * 8;
                const bf16x8 bh = *(const bf16x8*)&Bs[fo];
                const bf16x8 bl = *(const bf16x8*)&Bs[8192 + fo];
                acc[ct] = __builtin_amdgcn_mfma_f32_16x16x32_bf16(ah[ks], bh, acc[ct], 0, 0, 0);
                acc[ct] = __builtin_amdgcn_mfma_f32_16x16x32_bf16(ah[ks], bl, acc[ct], 0, 0, 0);
            }
        }
    }
#pragma unroll
    for (int ct = 0; ct < 8; ++ct) {
        const int c = ct * 16 + c16;
        const float b = bias ? bias[c] : 0.f;
#pragma unroll
        for (int r = 0; r < 4; ++r) {
            const int row = rb + kg * 4 + r;
            if (row < NN) {
                float v = acc[ct][r] + b;
                if (act == 1) v = fmaxf(v, 0.f);
                else if (act == 2) v = 1.f / (1.f + __expf(-v));
                if (obf) ((unsigned short*)out)[(size_t)row * ldo + co + c] = f2bf(v);
                else     ((float*)out)[(size_t)row * ldo + co + c] = v;
            }
        }
    }
}

// ---------------------------------------------------------------------------
// SPMM over bf16 H (row = 64 uints = 128 bf16), fused epilogue.
// obf: pack 2 bf16 into outb (ldo in uints); else float2 into outf (ldo floats).
// ---------------------------------------------------------------------------
__launch_bounds__(256)
__global__ void spmm_bf16(const unsigned int* __restrict__ H2,
                          const int* __restrict__ rp,
                          const int* __restrict__ ccol,
                          const float* __restrict__ cval,
                          const float* __restrict__ addend,
                          const float* __restrict__ pmask,
                          const int act, const int obf,
                          float* __restrict__ outf, unsigned int* __restrict__ outb,
                          const int ldo)
{
    const int w = (blockIdx.x * 256 + threadIdx.x) >> 6;
    if (w >= NN) return;
    const int lane = threadIdx.x & 63;
    const int s = rp[w], e = rp[w + 1];
    float ax = 0.f, ay = 0.f;
    int j = s;
    while (j < e) {
        int cnt = e - j; if (cnt > 8) cnt = 8;
        int cols[8]; float vals[8];
#pragma unroll
        for (int q = 0; q < 8; ++q) {
            if (q < cnt) { cols[q] = ccol[j + q]; vals[q] = cval[j + q]; }
        }
#pragma unroll
        for (int q = 0; q < 8; ++q) {
            if (q < cnt) {
                const unsigned u = H2[(size_t)cols[q] * 64 + lane];
                ax = fmaf(vals[q], __uint_as_float(u << 16), ax);
                ay = fmaf(vals[q], __uint_as_float(u & 0xFFFF0000u), ay);
            }
        }
        j += cnt;
    }
    if (addend) {
        const float2 t = *reinterpret_cast<const float2*>(addend + (size_t)w * DD + lane * 2);
        ax += t.x; ay += t.y;
    }
    if (pmask) {
        const float2 m = *reinterpret_cast<const float2*>(pmask + (size_t)w * DD + lane * 2);
        ax *= m.x; ay *= m.y;
    }
    if (act == 1) { ax = fmaxf(ax, 0.f); ay = fmaxf(ay, 0.f); }
    if (obf) {
        outb[(size_t)w * ldo + lane] = (unsigned)f2bf(ax) | ((unsigned)f2bf(ay) << 16);
    } else {
        float2 o; o.x = ax; o.y = ay;
        *reinterpret_cast<float2*>(outf + (size_t)w * ldo + lane * 2) = o;
    }
}

// ---------------------------------------------------------------------------
// CSR build kernels (unchanged)
// ---------------------------------------------------------------------------
__global__ void hist_k(const int* __restrict__ dstI, int* __restrict__ counts) {
    const int e = blockIdx.x * 256 + threadIdx.x;
    if (e < EE) atomicAdd(&counts[dstI[e]], 1);
}

__global__ void block_sums_k(const int* __restrict__ counts, int* __restrict__ bsum) {
    __shared__ int s[256];
    const int t = threadIdx.x;
    const int i = blockIdx.x * 256 + t;
    s[t] = (i < NN) ? counts[i] : 0;
    __syncthreads();
    for (int off = 128; off > 0; off >>= 1) {
        if (t < off) s[t] += s[t + off];
        __syncthreads();
    }
    if (t == 0) bsum[blockIdx.x] = s[0];
}

__global__ void scan_bsums_k(const int* __restrict__ bsum, int* __restrict__ bpre, const int nb) {
    __shared__ int s[512];
    const int t = threadIdx.x;
    s[t] = (t < nb) ? bsum[t] : 0;
    __syncthreads();
    for (int off = 1; off < 512; off <<= 1) {
        const int tmp = (t >= off) ? s[t - off] : 0;
        __syncthreads();
        s[t] += tmp;
        __syncthreads();
    }
    if (t < nb) bpre[t] = (t == 0) ? 0 : s[t - 1];
}

__global__ void scan_final_k(const int* __restrict__ counts, const int* __restrict__ bpre,
                             int* __restrict__ rowptr, int* __restrict__ nextc) {
    __shared__ int s[256];
    const int t = threadIdx.x;
    const int i = blockIdx.x * 256 + t;
    const int v = (i < NN) ? counts[i] : 0;
    s[t] = v;
    __syncthreads();
    for (int off = 1; off < 256; off <<= 1) {
        const int tmp = (t >= off) ? s[t - off] : 0;
        __syncthreads();
        s[t] += tmp;
        __syncthreads();
    }
    const int excl = s[t] - v + bpre[blockIdx.x];
    if (i < NN) { rowptr[i] = excl; nextc[i] = excl; }
    if (i == NN - 1) rowptr[NN] = EE;
}

__global__ void scatter_k(const int* __restrict__ srcI, const int* __restrict__ dstI,
                          const float* __restrict__ ea, int* __restrict__ nextc,
                          int* __restrict__ ccol, float* __restrict__ cval) {
    const int e = blockIdx.x * 256 + threadIdx.x;
    if (e >= EE) return;
    const int d = dstI[e];
    const int p = atomicAdd(&nextc[d], 1);
    ccol[p] = srcI[e];
    cval[p] = ea[e];
}

// ---------------------------------------------------------------------------
extern "C" void kernel_launch(void* const* d_in, const int* in_sizes, int n_in,
                              void* d_out, int out_size, void* d_ws, size_t ws_size,
                              hipStream_t stream)
{
    const float* x_in0      = (const float*)d_in[0];
    const float* edge_attr  = (const float*)d_in[1];
    const int*   edge_index = (const int*)d_in[2];
    const float* l1_b       = (const float*)d_in[6];
    const float* l2_b       = (const float*)d_in[8];
    const float* mlp1_b     = (const float*)d_in[10];
    const float* mlp2_b     = (const float*)d_in[12];
    const float* post1_b    = (const float*)d_in[14];
    const float* post2_b    = (const float*)d_in[16];

    const int* srcI = edge_index;
    const int* dstI = edge_index + EE;

    float* x_ws = (float*)d_out;   // x ping buffer (in-place-safe, see r0 notes)

    float*          maskb  = (float*)d_ws;                     // [NN][DD] f32
    float*          tbuf   = maskb + (size_t)NN * DD;          // [NN][DD] f32
    unsigned short* h16    = (unsigned short*)(tbuf + (size_t)NN * DD);  // [NN][DD]
    unsigned short* cat16  = h16 + (size_t)NN * DD;            // [NN][2*DD]
    unsigned short* gh16   = cat16 + (size_t)NN * 2 * DD;      // [NN][DD]
    unsigned short* Wh_all = gh16 + (size_t)NN * DD;           // 376832
    unsigned short* Wl_all = Wh_all + 376832;                  // 376832
    float* cval   = (float*)(Wl_all + 376832);                 // [EE]
    int*   ccol   = (int*)(cval + EE);                         // [EE]
    int*   rowptr = ccol + EE;                                 // [NN+1]
    int*   nextc  = rowptr + (NN + 1);                         // [NN]
    int*   counts = nextc + NN;                                // [NN]
    int*   bsum   = counts + NN;                               // [512]
    int*   bpre   = bsum + 512;                                // [512]

    wfrag_k<<<92, 256, 0, stream>>>((const float*)d_in[5], (const float*)d_in[7],
                                    (const float*)d_in[9], (const float*)d_in[11],
                                    (const float*)d_in[3], (const float*)d_in[4],
                                    (const float*)d_in[13], (const float*)d_in[15],
                                    Wh_all, Wl_all);
    hipMemsetAsync(counts, 0, NN * sizeof(int), stream);
    hist_k      <<<(EE + 255) / 256, 256, 0, stream>>>(dstI, counts);
    block_sums_k<<<NB_SCAN, 256, 0, stream>>>(counts, bsum);
    scan_bsums_k<<<1, 512, 0, stream>>>(bsum, bpre, NB_SCAN);
    scan_final_k<<<NB_SCAN, 256, 0, stream>>>(counts, bpre, rowptr, nextc);
    scatter_k   <<<(EE + 255) / 256, 256, 0, stream>>>(srcI, dstI, edge_attr, nextc, ccol, cval);

    const int GG = (NN + 63) / 64;        // 1563 blocks (64 rows each)
    const int SPMM_GRID = NN * 64 / 256;  // 25000

    const size_t F_L1 = 0, F_L2 = 49152, F_M1 = 98304, F_M2 = 196608;
    const size_t F_CV = 245760, F_CL = 294912, F_P1 = 344064, F_P2 = 360448;

    for (int i = 0; i < 3; ++i) {
        const float* xc = (i == 0) ? x_in0 : x_ws;
        const float* pm = (i == 0) ? nullptr : maskb;
        const size_t o128 = (size_t)i * 16384, o256 = (size_t)i * 32768;
        // dual: h16 = bf16(xm@l1+b1) ; cat16[:,128:] = bf16(xm@l2+b2)
        gemm_f32A<4, 1, 0, 4><<<GG, 256, 0, stream>>>(xc, pm,
            Wh_all + F_L1 + o128, Wl_all + F_L1 + o128, l1_b + (size_t)i * DD, 0, 1, h16, DD, 0,
            Wh_all + F_L2 + o128, Wl_all + F_L2 + o128, l2_b + (size_t)i * DD, 1, cat16, 2 * DD, DD);
        // cat16[:,0:128] = bf16(agg(h))
        spmm_bf16<<<SPMM_GRID, 256, 0, stream>>>((const unsigned*)h16, rowptr, ccol, cval,
            nullptr, nullptr, 0, 1, nullptr, (unsigned*)cat16, 2 * DD / 2);
        // gh16 = bf16(relu(relu(cat)@mlp1+b))
        gemm_bf16A<8, 4><<<GG, 256, 0, stream>>>(cat16, 1,
            Wh_all + F_M1 + o256, Wl_all + F_M1 + o256, mlp1_b + (size_t)i * DD, 1, 1, gh16, DD, 0);
        // mask = sigmoid(gh@mlp2+b)  (fp32)
        gemm_bf16A<4, 4><<<GG, 256, 0, stream>>>(gh16, 0,
            Wh_all + F_M2 + o128, Wl_all + F_M2 + o128, mlp2_b + (size_t)i * DD, 2, 0, maskb, DD, 0);
        // dual RAW1: h16 = bf16((x*mask)@convw) ; tbuf = x@convlin (fp32)
        gemm_f32A<4, 1, 1, 3><<<GG, 256, 0, stream>>>(xc, maskb,
            Wh_all + F_CV + o128, Wl_all + F_CV + o128, nullptr, 0, 1, h16, DD, 0,
            Wh_all + F_CL + o128, Wl_all + F_CL + o128, nullptr, 0, tbuf, DD, 0);
        // x = relu((agg(h2) + t) * mask)  (fp32 -> x_ws)
        spmm_bf16<<<SPMM_GRID, 256, 0, stream>>>((const unsigned*)h16, rowptr, ccol, cval,
            tbuf, maskb, 1, 0, x_ws, nullptr, DD);
    }
    // gh16 = bf16(relu(x@post1+b))
    gemm_f32A<4, 0, 0, 4><<<GG, 256, 0, stream>>>(x_ws, nullptr,
        Wh_all + F_P1, Wl_all + F_P1, post1_b, 1, 1, gh16, DD, 0,
        nullptr, nullptr, nullptr, 0, nullptr, 0, 0);
    // out = gh@post2+b  (fp32 -> d_out)
    gemm_bf16A<4, 4><<<GG, 256, 0, stream>>>(gh16, 0,
        Wh_all + F_P2, Wl_all + F_P2, post2_b, 0, 0, (float*)d_out, DD, 0);

    (void)in_sizes; (void)n_in; (void)out_size; (void)ws_size;
}